// Round 2
// baseline (1068.585 us; speedup 1.0000x reference)
//
#include <hip/hip_runtime.h>
#include <stdint.h>

typedef __bf16 bf16;
typedef __bf16 bf16x8 __attribute__((ext_vector_type(8)));
typedef __bf16 bf16x4 __attribute__((ext_vector_type(4)));
typedef float f32x4 __attribute__((ext_vector_type(4)));
typedef float f32x16 __attribute__((ext_vector_type(16)));
typedef unsigned int u32;

#define S 2048
#define DM 2048
#define NH 32
#define HD 64

// async global->LDS, 16B per lane; lds base must be wave-uniform
#define GLDS16(g, l)                                                   \
  __builtin_amdgcn_global_load_lds(                                    \
      (const __attribute__((address_space(1))) void*)(g),              \
      (__attribute__((address_space(3))) void*)(l), 16, 0, 0)

// ---------------------------------------------------------------------------
// Bucket table: T5 bidirectional buckets as threshold function of dist = k-q.
// Boundaries 12,16,23,32,46,64,91 (f32 knife-edge verified).
// ---------------------------------------------------------------------------
__device__ __forceinline__ int bucket_of(int dist) {
  int rel = dist > 0 ? 16 : 0;
  int ad = dist < 0 ? -dist : dist;
  int b;
  if (ad < 8)       b = ad;
  else if (ad < 12) b = 8;
  else if (ad < 16) b = 9;
  else if (ad < 23) b = 10;
  else if (ad < 32) b = 11;
  else if (ad < 46) b = 12;
  else if (ad < 64) b = 13;
  else if (ad < 91) b = 14;
  else              b = 15;
  return rel + b;
}

__global__ void bucket_kernel(int8_t* __restrict__ table) {
  int i = blockIdx.x * 256 + threadIdx.x;
  if (i < 4095) table[i] = (int8_t)bucket_of(i - 2047);
}

// ---------------------------------------------------------------------------
// Fused f32 -> bf16 cast: 6 equal segments (x as 2, wq, wk, wv, wo) into the
// contiguous arena [xb | wqb | wkb | wvb | wob].
// ---------------------------------------------------------------------------
__global__ void cast6(const float* __restrict__ s0, const float* __restrict__ s1,
                      const float* __restrict__ s2, const float* __restrict__ s3,
                      const float* __restrict__ s4, const float* __restrict__ s5,
                      bf16* __restrict__ dst) {
  int seg = blockIdx.y;
  const float* src = seg == 0 ? s0 : seg == 1 ? s1 : seg == 2 ? s2
                   : seg == 3 ? s3 : seg == 4 ? s4 : s5;
  int i = blockIdx.x * 256 + threadIdx.x;  // < WSZ/4
  float4 v = ((const float4*)src)[i];
  bf16x4 o;
  o[0] = (bf16)v.x; o[1] = (bf16)v.y; o[2] = (bf16)v.z; o[3] = (bf16)v.w;
  *(bf16x4*)(dst + (size_t)seg * DM * DM + (size_t)i * 4) = o;
}

// ---------------------------------------------------------------------------
// position_bias writer (f32, exact). Runs LAST (pb region is scratch before).
// ---------------------------------------------------------------------------
__global__ void pb_kernel(const float* __restrict__ rel_bias,
                          const int8_t* __restrict__ table,
                          float* __restrict__ pb) {
  int q = blockIdx.x, h = blockIdx.y;
  __shared__ float bias_h[32];
  if (threadIdx.x < 32) bias_h[threadIdx.x] = rel_bias[threadIdx.x * NH + h];
  __syncthreads();
  int k0 = threadIdx.x * 8;
  const int8_t* tb = table + (2047 - q);
  float4 a, bq;
  a.x = bias_h[tb[k0 + 0]]; a.y = bias_h[tb[k0 + 1]];
  a.z = bias_h[tb[k0 + 2]]; a.w = bias_h[tb[k0 + 3]];
  bq.x = bias_h[tb[k0 + 4]]; bq.y = bias_h[tb[k0 + 5]];
  bq.z = bias_h[tb[k0 + 6]]; bq.w = bias_h[tb[k0 + 7]];
  float* row = pb + (size_t)h * S * S + (size_t)q * S + k0;
  *(float4*)row = a;
  *(float4*)(row + 4) = bq;
}

// ---------------------------------------------------------------------------
// GEMM body: C[M,N] = A[M,K] * W[N,K]^T. m97-style width-16 global_load_lds
// into unpadded [128][32] tiles. 128x128 tile, BK=32, 4 waves, 4x4 MFMA/wave.
// ---------------------------------------------------------------------------
template <typename OutT>
__device__ __forceinline__ void gemm_body(const bf16* __restrict__ A,
                                          const bf16* __restrict__ W,
                                          OutT* __restrict__ C, int N, int K,
                                          int m0, int n0) {
  __shared__ bf16 As[128 * 32];
  __shared__ bf16 Ws[128 * 32];
  int t = threadIdx.x;
  int wave = t >> 6, lane = t & 63;
  int quad = lane >> 4, l16 = lane & 15;
  int wm = (wave >> 1) * 64, wn = (wave & 1) * 64;

  f32x4 zero = {0.f, 0.f, 0.f, 0.f};
  f32x4 acc[4][4];
  for (int i = 0; i < 4; i++)
    for (int j = 0; j < 4; j++) acc[i][j] = zero;

  int srow = wave * 32 + (lane >> 2);
  int scol = (lane & 3) * 8;
  const bf16* Ag = A + (size_t)(m0 + srow) * K + scol;
  const bf16* Wg = W + (size_t)(n0 + srow) * K + scol;
  bf16* AsBase = &As[(wave * 32) * 32];
  bf16* WsBase = &Ws[(wave * 32) * 32];

  for (int k0 = 0; k0 < K; k0 += 32) {
    __syncthreads();
    GLDS16(Ag + k0, AsBase);
    GLDS16(Ag + (size_t)16 * K + k0, AsBase + 16 * 32);
    GLDS16(Wg + k0, WsBase);
    GLDS16(Wg + (size_t)16 * K + k0, WsBase + 16 * 32);
    __syncthreads();
    bf16x8 af[4], wf[4];
    for (int i = 0; i < 4; i++)
      af[i] = *(const bf16x8*)&As[(wm + i * 16 + l16) * 32 + quad * 8];
    for (int j = 0; j < 4; j++)
      wf[j] = *(const bf16x8*)&Ws[(wn + j * 16 + l16) * 32 + quad * 8];
    for (int i = 0; i < 4; i++)
      for (int j = 0; j < 4; j++)
        acc[i][j] = __builtin_amdgcn_mfma_f32_16x16x32_bf16(af[i], wf[j],
                                                            acc[i][j], 0, 0, 0);
  }
  for (int i = 0; i < 4; i++)
    for (int j = 0; j < 4; j++) {
      int col = n0 + wn + j * 16 + l16;
      for (int r = 0; r < 4; r++) {
        int row = m0 + wm + i * 16 + quad * 4 + r;
        C[(size_t)row * N + col] = (OutT)acc[i][j][r];
      }
    }
}

// QKV fused: grid.z selects weight; outputs are contiguous PROJ-sized chunks.
__global__ __launch_bounds__(256, 2)
void gemm_qkv(const bf16* __restrict__ A, const bf16* __restrict__ W0,
              const bf16* __restrict__ W1, const bf16* __restrict__ W2,
              bf16* __restrict__ C) {
  const bf16* W = blockIdx.z == 0 ? W0 : (blockIdx.z == 1 ? W1 : W2);
  bf16* Cz = C + (size_t)blockIdx.z * (size_t)2 * S * DM;
  gemm_body<bf16>(A, W, Cz, DM, DM, blockIdx.y * 128, blockIdx.x * 128);
}

__global__ __launch_bounds__(256, 2)
void gemm_out(const bf16* __restrict__ A, const bf16* __restrict__ W,
              float* __restrict__ C) {
  gemm_body<float>(A, W, C, DM, DM, blockIdx.y * 128, blockIdx.x * 128);
}

// ---------------------------------------------------------------------------
// Per-head V transpose: Vt[b][h][d][s] = V[b*S+s][h*64+d].
// ---------------------------------------------------------------------------
__global__ void transpose_v(const bf16* __restrict__ V, bf16* __restrict__ Vt) {
  int s0 = blockIdx.x * 64, h = blockIdx.y, b = blockIdx.z;
  __shared__ bf16 tile[64][72];
  int t = threadIdx.x;
  int r = t >> 3, c = (t & 7) * 8;
  for (int half = 0; half < 2; half++) {
    int row = half * 32 + r;
    *(bf16x8*)&tile[row][c] =
        *(const bf16x8*)(V + ((size_t)(b * S + s0 + row)) * DM + h * HD + c);
  }
  __syncthreads();
  int d = t >> 2, sc = (t & 3) * 16;
  for (int half = 0; half < 2; half++) {
    bf16x8 o;
    for (int j = 0; j < 8; j++) o[j] = tile[sc + half * 8 + j][d];
    *(bf16x8*)(Vt + ((size_t)((b * NH + h) * HD + d)) * S + s0 + sc + half * 8) = o;
  }
}

// ---------------------------------------------------------------------------
// Flash attention v6: v4 structure (S^T orientation, constant-shift softmax,
// shfl-based P exchange, padded LDS tiles, reg-roundtrip staging) + explicit
// T14 async-STAGE split: global loads for tile t+1 are issued right after the
// "tile t ready" barrier, so HBM latency hides under the full QK/softmax/PV
// compute phase; the ds_writes at the top of iter t+1 consume them after the
// compiler-inserted vmcnt wait. s_setprio(1) wraps the MFMA clusters.
// LDS 40 KB -> 4 blocks/CU, grid fully resident.
// ---------------------------------------------------------------------------
__global__ __launch_bounds__(256, 4)
void attn_kernel(const bf16* __restrict__ Q, const bf16* __restrict__ K,
                 const bf16* __restrict__ Vt, const float* __restrict__ rel_bias,
                 const int8_t* __restrict__ table, bf16* __restrict__ ctx_out) {
  int q0 = blockIdx.x * 128;
  int h = blockIdx.y, b = blockIdx.z;
  int t = threadIdx.x;
  int wave = t >> 6, lane = t & 63;
  int l31 = lane & 31, hi = lane >> 5;

  __shared__ bf16 Ks[128 * 72];     // [key][d] pad->72       18432 B
  __shared__ bf16 Vs[64 * 136];     // [d][key] pad->136      17408 B
  __shared__ float bias_s[32];
  __shared__ uint8_t tab_s[4096];

  if (t < 32) bias_s[t] = rel_bias[t * NH + h];
  for (int i = t; i < 4095; i += 256) tab_s[i] = (uint8_t)table[i];

  int q = q0 + wave * 32 + l31;
  const bf16* qp = Q + ((size_t)(b * S + q)) * DM + h * HD + hi * 8;
  bf16x8 bq[4];
  for (int ds = 0; ds < 4; ds++) bq[ds] = *(const bf16x8*)(qp + ds * 16);

  f32x16 ctx[2];
  for (int i = 0; i < 16; i++) { ctx[0][i] = 0.f; ctx[1][i] = 0.f; }
  float l_run = 1e-30f;

  // staging: K 128x64 (2 thr/row, 4 x b128 each), V 64x128 (4 thr/row)
  int kr = t >> 1, kc = (t & 1) * 32;
  int vr = t >> 2, vc = (t & 3) * 32;
  const bf16* Kg = K + ((size_t)(b * S + kr)) * DM + h * HD + kc;
  const bf16* Vg = Vt + ((size_t)((b * NH + h) * HD + vr)) * S + vc;

  // ---- T14 prologue: load tile 0 into registers ----
  bf16x8 kreg[4], vreg[4];
  {
    kreg[0] = *(const bf16x8*)(Kg);
    kreg[1] = *(const bf16x8*)(Kg + 8);
    kreg[2] = *(const bf16x8*)(Kg + 16);
    kreg[3] = *(const bf16x8*)(Kg + 24);
    vreg[0] = *(const bf16x8*)(Vg);
    vreg[1] = *(const bf16x8*)(Vg + 8);
    vreg[2] = *(const bf16x8*)(Vg + 16);
    vreg[3] = *(const bf16x8*)(Vg + 24);
  }

  for (int k0 = 0; k0 < S; k0 += 128) {
    __syncthreads();  // prior iter's LDS reads done
    {
      bf16* kd = &Ks[kr * 72 + kc];
      *(bf16x8*)(kd)      = kreg[0];
      *(bf16x8*)(kd + 8)  = kreg[1];
      *(bf16x8*)(kd + 16) = kreg[2];
      *(bf16x8*)(kd + 24) = kreg[3];
      bf16* vd = &Vs[vr * 136 + vc];
      *(bf16x8*)(vd)      = vreg[0];
      *(bf16x8*)(vd + 8)  = vreg[1];
      *(bf16x8*)(vd + 16) = vreg[2];
      *(bf16x8*)(vd + 24) = vreg[3];
    }
    __syncthreads();

    // ---- T14 issue-early: next tile's loads fly under this tile's compute
    if (k0 + 128 < S) {
      const bf16* kp = Kg + (size_t)(k0 + 128) * DM;
      kreg[0] = *(const bf16x8*)(kp);
      kreg[1] = *(const bf16x8*)(kp + 8);
      kreg[2] = *(const bf16x8*)(kp + 16);
      kreg[3] = *(const bf16x8*)(kp + 24);
      const bf16* vp = Vg + k0 + 128;
      vreg[0] = *(const bf16x8*)(vp);
      vreg[1] = *(const bf16x8*)(vp + 8);
      vreg[2] = *(const bf16x8*)(vp + 16);
      vreg[3] = *(const bf16x8*)(vp + 24);
    }

    int dmax = k0 + 127 - q0, dmin = k0 - (q0 + 127);
    bool cflat = (dmax <= -91) || (dmin >= 91);
    float cshift = ((dmax <= -91) ? bias_s[15] : bias_s[31]) - 40.f;

    for (int kt = 0; kt < 4; kt++) {
      // S^T tile: A = K rows (32 keys), B = Q regs (32 q)
      f32x16 sc;
      for (int i = 0; i < 16; i++) sc[i] = 0.f;
      int krb = (kt * 32 + l31) * 72 + hi * 8;
      bf16x8 ak[4];
#pragma unroll
      for (int ds = 0; ds < 4; ds++)
        ak[ds] = *(const bf16x8*)&Ks[krb + ds * 16];
      __builtin_amdgcn_s_setprio(1);
#pragma unroll
      for (int ds = 0; ds < 4; ds++)
        sc = __builtin_amdgcn_mfma_f32_32x32x16_bf16(ak[ds], bq[ds], sc, 0, 0, 0);
      __builtin_amdgcn_s_setprio(0);
      // softmax (constant shift) + pack P^T groups: reg 4g+r -> key
      // (r&3)+8g+4hi; ua/ub[g] hold bf16(p) pairs
      int keyb = k0 + kt * 32 + 4 * hi - q + 2047;
      u32 ua[4], ub[4];
      for (int g = 0; g < 4; g++) {
        float p[4];
        for (int r = 0; r < 4; r++) {
          float v = sc[g * 4 + r];
          if (cflat) p[r] = __expf(v + cshift);
          else       p[r] = __expf(v + bias_s[tab_s[keyb + 8 * g + r]] - 40.f);
          l_run += p[r];
        }
        union { bf16x4 v4; u32 w[2]; } pk;
        pk.v4[0] = (bf16)p[0]; pk.v4[1] = (bf16)p[1];
        pk.v4[2] = (bf16)p[2]; pk.v4[3] = (bf16)p[3];
        ua[g] = pk.w[0]; ub[g] = pk.w[1];
      }
      // PV per 16-key chunk c: B-frag needs group G=2c+hi from BOTH lanes of
      // the (q, hi)<->(q, hi^1) pair -> exchange the partner-needed group.
      for (int c = 0; c < 2; c++) {
        u32 ka = hi ? ua[2 * c + 1] : ua[2 * c];
        u32 kb = hi ? ub[2 * c + 1] : ub[2 * c];
        u32 sa = hi ? ua[2 * c]     : ua[2 * c + 1];
        u32 sb = hi ? ub[2 * c]     : ub[2 * c + 1];
        u32 ra = (u32)__shfl_xor((int)sa, 32, 64);
        u32 rb = (u32)__shfl_xor((int)sb, 32, 64);
        union { u32 w[4]; bf16x8 v; } pf;
        pf.w[0] = hi ? ra : ka;   // j0-3 from hi_src=0 lane
        pf.w[1] = hi ? rb : kb;
        pf.w[2] = hi ? ka : ra;   // j4-7 from hi_src=1 lane
        pf.w[3] = hi ? kb : rb;
        bf16x8 av0 = *(const bf16x8*)&Vs[(0 * 32 + l31) * 136 + kt * 32 +
                                         c * 16 + hi * 8];
        bf16x8 av1 = *(const bf16x8*)&Vs[(1 * 32 + l31) * 136 + kt * 32 +
                                         c * 16 + hi * 8];
        __builtin_amdgcn_s_setprio(1);
        ctx[0] = __builtin_amdgcn_mfma_f32_32x32x16_bf16(av0, pf.v, ctx[0], 0, 0, 0);
        ctx[1] = __builtin_amdgcn_mfma_f32_32x32x16_bf16(av1, pf.v, ctx[1], 0, 0, 0);
        __builtin_amdgcn_s_setprio(0);
      }
    }
  }

  // lanes (q,0)/(q,1) hold disjoint key subsets: pair-sum l
  l_run += __shfl_xor(l_run, 32, 64);
  float rl = 1.f / l_run;
  // ctx^T C-layout: col=q=l31, row d = (r&3)+8g+4hi (+32dt)
  for (int dt = 0; dt < 2; dt++)
    for (int g = 0; g < 4; g++) {
      bf16x4 o;
      for (int r = 0; r < 4; r++) o[r] = (bf16)(ctx[dt][g * 4 + r] * rl);
      *(bf16x4*)&ctx_out[((size_t)(b * S + q)) * DM + h * HD + dt * 32 +
                         8 * g + 4 * hi] = o;
    }
}

// ---------------------------------------------------------------------------
extern "C" void kernel_launch(void* const* d_in, const int* in_sizes, int n_in,
                              void* d_out, int out_size, void* d_ws, size_t ws_size,
                              hipStream_t stream) {
  const float* x  = (const float*)d_in[0];
  const float* wq = (const float*)d_in[1];
  const float* wk = (const float*)d_in[2];
  const float* wv = (const float*)d_in[3];
  const float* wo = (const float*)d_in[4];
  const float* rb = (const float*)d_in[5];

  float* out = (float*)d_out;               // [2*2048, 2048] f32
  float* pb  = out + (size_t)2 * S * DM;    // [32, 2048, 2048] f32 — written LAST

  const size_t PROJ = (size_t)2 * S * DM;   // 8,388,608
  const size_t WSZ  = (size_t)DM * DM;      // 4,194,304
  bf16* arena = (bf16*)pb;                  // scratch aliased into pb region
  bf16* xb   = arena;
  bf16* wqb  = xb + PROJ;
  bf16* wkb  = wqb + WSZ;
  bf16* wvb  = wkb + WSZ;
  bf16* wob  = wvb + WSZ;
  bf16* qs   = wob + WSZ;
  bf16* ks   = qs + PROJ;
  bf16* vs   = ks + PROJ;
  bf16* ctxs = vs + PROJ;
  bf16* vts  = ctxs + PROJ;                 // [B,H,64,S]
  int8_t* table = (int8_t*)d_ws;

  bucket_kernel<<<16, 256, 0, stream>>>(table);

  cast6<<<dim3((int)(WSZ / 4) / 256, 6), 256, 0, stream>>>(
      x, x + WSZ, wq, wk, wv, wo, arena);

  gemm_qkv<<<dim3(DM / 128, (2 * S) / 128, 3), 256, 0, stream>>>(xb, wqb, wkb,
                                                                 wvb, qs);

  transpose_v<<<dim3(S / 64, NH, 2), 256, 0, stream>>>(vs, vts);

  attn_kernel<<<dim3(S / 128, NH, 2), 256, 0, stream>>>(qs, ks, vts, rb, table,
                                                        ctxs);

  gemm_out<<<dim3(DM / 128, (2 * S) / 128), 256, 0, stream>>>(ctxs, wob, out);

  pb_kernel<<<dim3(S, NH), 256, 0, stream>>>(rb, table, pb);
}

// Round 3
// 906.378 us; speedup vs baseline: 1.1790x; 1.1790x over previous
//
#include <hip/hip_runtime.h>
#include <stdint.h>

typedef __bf16 bf16;
typedef __bf16 bf16x8 __attribute__((ext_vector_type(8)));
typedef __bf16 bf16x4 __attribute__((ext_vector_type(4)));
typedef float f32x4 __attribute__((ext_vector_type(4)));
typedef float f32x16 __attribute__((ext_vector_type(16)));
typedef unsigned int u32;

#define S 2048
#define DM 2048
#define NH 32
#define HD 64

// async global->LDS, 16B per lane; lds base must be wave-uniform
#define GLDS16(g, l)                                                   \
  __builtin_amdgcn_global_load_lds(                                    \
      (const __attribute__((address_space(1))) void*)(g),              \
      (__attribute__((address_space(3))) void*)(l), 16, 0, 0)

// ---------------------------------------------------------------------------
// Bucket table: T5 bidirectional buckets as threshold function of dist = k-q.
// Boundaries 12,16,23,32,46,64,91 (f32 knife-edge verified).
// ---------------------------------------------------------------------------
__device__ __forceinline__ int bucket_of(int dist) {
  int rel = dist > 0 ? 16 : 0;
  int ad = dist < 0 ? -dist : dist;
  int b;
  if (ad < 8)       b = ad;
  else if (ad < 12) b = 8;
  else if (ad < 16) b = 9;
  else if (ad < 23) b = 10;
  else if (ad < 32) b = 11;
  else if (ad < 46) b = 12;
  else if (ad < 64) b = 13;
  else if (ad < 91) b = 14;
  else              b = 15;
  return rel + b;
}

__global__ void bucket_kernel(int8_t* __restrict__ table) {
  int i = blockIdx.x * 256 + threadIdx.x;
  if (i < 4095) table[i] = (int8_t)bucket_of(i - 2047);
}

// ---------------------------------------------------------------------------
// Fused f32 -> bf16 cast: 6 equal segments (x as 2, wq, wk, wv, wo) into the
// contiguous arena [xb | wqb | wkb | wvb | wob].
// ---------------------------------------------------------------------------
__global__ void cast6(const float* __restrict__ s0, const float* __restrict__ s1,
                      const float* __restrict__ s2, const float* __restrict__ s3,
                      const float* __restrict__ s4, const float* __restrict__ s5,
                      bf16* __restrict__ dst) {
  int seg = blockIdx.y;
  const float* src = seg == 0 ? s0 : seg == 1 ? s1 : seg == 2 ? s2
                   : seg == 3 ? s3 : seg == 4 ? s4 : s5;
  int i = blockIdx.x * 256 + threadIdx.x;  // < WSZ/4
  float4 v = ((const float4*)src)[i];
  bf16x4 o;
  o[0] = (bf16)v.x; o[1] = (bf16)v.y; o[2] = (bf16)v.z; o[3] = (bf16)v.w;
  *(bf16x4*)(dst + (size_t)seg * DM * DM + (size_t)i * 4) = o;
}

// ---------------------------------------------------------------------------
// position_bias writer (f32, exact). Runs LAST (pb region is scratch before).
// ---------------------------------------------------------------------------
__global__ void pb_kernel(const float* __restrict__ rel_bias,
                          const int8_t* __restrict__ table,
                          float* __restrict__ pb) {
  int q = blockIdx.x, h = blockIdx.y;
  __shared__ float bias_h[32];
  if (threadIdx.x < 32) bias_h[threadIdx.x] = rel_bias[threadIdx.x * NH + h];
  __syncthreads();
  int k0 = threadIdx.x * 8;
  const int8_t* tb = table + (2047 - q);
  float4 a, bq;
  a.x = bias_h[tb[k0 + 0]]; a.y = bias_h[tb[k0 + 1]];
  a.z = bias_h[tb[k0 + 2]]; a.w = bias_h[tb[k0 + 3]];
  bq.x = bias_h[tb[k0 + 4]]; bq.y = bias_h[tb[k0 + 5]];
  bq.z = bias_h[tb[k0 + 6]]; bq.w = bias_h[tb[k0 + 7]];
  float* row = pb + (size_t)h * S * S + (size_t)q * S + k0;
  *(float4*)row = a;
  *(float4*)(row + 4) = bq;
}

// ---------------------------------------------------------------------------
// GEMM body: C[M,N] = A[M,K] * W[N,K]^T. m97-style width-16 global_load_lds
// into unpadded [128][32] tiles. 128x128 tile, BK=32, 4 waves, 4x4 MFMA/wave.
// TRANSV: write output in Vt[b][h][d][s] layout instead (per-lane bf16x4 of 4
// consecutive s at fixed d is contiguous -> 8B stores, 16x32B segments/wave).
// ---------------------------------------------------------------------------
template <typename OutT, bool TRANSV>
__device__ __forceinline__ void gemm_body(const bf16* __restrict__ A,
                                          const bf16* __restrict__ W,
                                          OutT* __restrict__ C,
                                          bf16* __restrict__ Vt,
                                          bf16* __restrict__ As,
                                          bf16* __restrict__ Ws, int N, int K,
                                          int m0, int n0) {
  int t = threadIdx.x;
  int wave = t >> 6, lane = t & 63;
  int quad = lane >> 4, l16 = lane & 15;
  int wm = (wave >> 1) * 64, wn = (wave & 1) * 64;

  f32x4 zero = {0.f, 0.f, 0.f, 0.f};
  f32x4 acc[4][4];
  for (int i = 0; i < 4; i++)
    for (int j = 0; j < 4; j++) acc[i][j] = zero;

  int srow = wave * 32 + (lane >> 2);
  int scol = (lane & 3) * 8;
  const bf16* Ag = A + (size_t)(m0 + srow) * K + scol;
  const bf16* Wg = W + (size_t)(n0 + srow) * K + scol;
  bf16* AsBase = &As[(wave * 32) * 32];
  bf16* WsBase = &Ws[(wave * 32) * 32];

  for (int k0 = 0; k0 < K; k0 += 32) {
    __syncthreads();
    GLDS16(Ag + k0, AsBase);
    GLDS16(Ag + (size_t)16 * K + k0, AsBase + 16 * 32);
    GLDS16(Wg + k0, WsBase);
    GLDS16(Wg + (size_t)16 * K + k0, WsBase + 16 * 32);
    __syncthreads();
    bf16x8 af[4], wf[4];
    for (int i = 0; i < 4; i++)
      af[i] = *(const bf16x8*)&As[(wm + i * 16 + l16) * 32 + quad * 8];
    for (int j = 0; j < 4; j++)
      wf[j] = *(const bf16x8*)&Ws[(wn + j * 16 + l16) * 32 + quad * 8];
    for (int i = 0; i < 4; i++)
      for (int j = 0; j < 4; j++)
        acc[i][j] = __builtin_amdgcn_mfma_f32_16x16x32_bf16(af[i], wf[j],
                                                            acc[i][j], 0, 0, 0);
  }
  if constexpr (TRANSV) {
    // col = h*64+d, row = b*S+s; tiles never straddle the b boundary (128|2048)
    for (int i = 0; i < 4; i++)
      for (int j = 0; j < 4; j++) {
        int col = n0 + wn + j * 16 + l16;
        int hh = col >> 6, dd = col & 63;
        int row0 = m0 + wm + i * 16 + quad * 4;
        int bb = row0 >> 11, ss = row0 & 2047;
        bf16x4 o;
        for (int r = 0; r < 4; r++) o[r] = (bf16)acc[i][j][r];
        *(bf16x4*)&Vt[(((size_t)(bb * NH + hh)) * HD + dd) * S + ss] = o;
      }
  } else {
    for (int i = 0; i < 4; i++)
      for (int j = 0; j < 4; j++) {
        int col = n0 + wn + j * 16 + l16;
        for (int r = 0; r < 4; r++) {
          int row = m0 + wm + i * 16 + quad * 4 + r;
          C[(size_t)row * N + col] = (OutT)acc[i][j][r];
        }
      }
  }
}

// QKV fused: grid.z selects weight; q,k outputs contiguous PROJ chunks, v
// output written directly in transposed Vt[b][h][d][s] layout (no separate
// transpose kernel, no intermediate).
__global__ __launch_bounds__(256, 2)
void gemm_qkv(const bf16* __restrict__ A, const bf16* __restrict__ W0,
              const bf16* __restrict__ W1, const bf16* __restrict__ W2,
              bf16* __restrict__ C, bf16* __restrict__ Vt) {
  __shared__ bf16 As[128 * 32];
  __shared__ bf16 Ws[128 * 32];
  int m0 = blockIdx.y * 128, n0 = blockIdx.x * 128;
  if (blockIdx.z == 2) {
    gemm_body<bf16, true>(A, W2, (bf16*)nullptr, Vt, As, Ws, DM, DM, m0, n0);
  } else {
    const bf16* W = blockIdx.z == 0 ? W0 : W1;
    bf16* Cz = C + (size_t)blockIdx.z * (size_t)2 * S * DM;
    gemm_body<bf16, false>(A, W, Cz, (bf16*)nullptr, As, Ws, DM, DM, m0, n0);
  }
}

__global__ __launch_bounds__(256, 2)
void gemm_out(const bf16* __restrict__ A, const bf16* __restrict__ W,
              float* __restrict__ C) {
  __shared__ bf16 As[128 * 32];
  __shared__ bf16 Ws[128 * 32];
  gemm_body<float, false>(A, W, C, (bf16*)nullptr, As, Ws, DM, DM,
                          blockIdx.y * 128, blockIdx.x * 128);
}

// ---------------------------------------------------------------------------
// Flash attention v4 (reverted verbatim — the 911 µs version): 256 thr = 4
// waves, each wave owns 32 q rows x ALL 128 keys per iter. S^T orientation
// (q in-lane, zero reductions in loop), constant-shift softmax, P transposed
// C-layout -> B-layout via ONE shfl_xor(32) pair per 16-key chunk (no Ps LDS,
// no extra barrier, no end merge). LDS 40 KB -> 4 blocks/CU, grid resident.
// ---------------------------------------------------------------------------
__global__ __launch_bounds__(256, 4)
void attn_kernel(const bf16* __restrict__ Q, const bf16* __restrict__ K,
                 const bf16* __restrict__ Vt, const float* __restrict__ rel_bias,
                 const int8_t* __restrict__ table, bf16* __restrict__ ctx_out) {
  int q0 = blockIdx.x * 128;
  int h = blockIdx.y, b = blockIdx.z;
  int t = threadIdx.x;
  int wave = t >> 6, lane = t & 63;
  int l31 = lane & 31, hi = lane >> 5;

  __shared__ bf16 Ks[128 * 72];     // [key][d] pad->72       18432 B
  __shared__ bf16 Vs[64 * 136];     // [d][key] pad->136      17408 B
  __shared__ float bias_s[32];
  __shared__ uint8_t tab_s[4096];

  if (t < 32) bias_s[t] = rel_bias[t * NH + h];
  for (int i = t; i < 4095; i += 256) tab_s[i] = (uint8_t)table[i];

  int q = q0 + wave * 32 + l31;
  const bf16* qp = Q + ((size_t)(b * S + q)) * DM + h * HD + hi * 8;
  bf16x8 bq[4];
  for (int ds = 0; ds < 4; ds++) bq[ds] = *(const bf16x8*)(qp + ds * 16);

  f32x16 ctx[2];
  for (int i = 0; i < 16; i++) { ctx[0][i] = 0.f; ctx[1][i] = 0.f; }
  float l_run = 1e-30f;

  // staging: K 128x64 (2 thr/row, 4 x b128 each), V 64x128 (4 thr/row)
  int kr = t >> 1, kc = (t & 1) * 32;
  int vr = t >> 2, vc = (t & 3) * 32;
  const bf16* Kg = K + ((size_t)(b * S + kr)) * DM + h * HD + kc;
  const bf16* Vg = Vt + ((size_t)((b * NH + h) * HD + vr)) * S + vc;

  for (int k0 = 0; k0 < S; k0 += 128) {
    __syncthreads();  // prior iter's LDS reads done
    {
      const bf16* kp = Kg + (size_t)k0 * DM;
      bf16* kd = &Ks[kr * 72 + kc];
      *(bf16x8*)(kd)      = *(const bf16x8*)(kp);
      *(bf16x8*)(kd + 8)  = *(const bf16x8*)(kp + 8);
      *(bf16x8*)(kd + 16) = *(const bf16x8*)(kp + 16);
      *(bf16x8*)(kd + 24) = *(const bf16x8*)(kp + 24);
      const bf16* vp = Vg + k0;
      bf16* vd = &Vs[vr * 136 + vc];
      *(bf16x8*)(vd)      = *(const bf16x8*)(vp);
      *(bf16x8*)(vd + 8)  = *(const bf16x8*)(vp + 8);
      *(bf16x8*)(vd + 16) = *(const bf16x8*)(vp + 16);
      *(bf16x8*)(vd + 24) = *(const bf16x8*)(vp + 24);
    }
    __syncthreads();

    int dmax = k0 + 127 - q0, dmin = k0 - (q0 + 127);
    bool cflat = (dmax <= -91) || (dmin >= 91);
    float cshift = ((dmax <= -91) ? bias_s[15] : bias_s[31]) - 40.f;

    for (int kt = 0; kt < 4; kt++) {
      // S^T tile: A = K rows (32 keys), B = Q regs (32 q)
      f32x16 sc;
      for (int i = 0; i < 16; i++) sc[i] = 0.f;
      int krb = (kt * 32 + l31) * 72 + hi * 8;
      for (int ds = 0; ds < 4; ds++) {
        bf16x8 ak = *(const bf16x8*)&Ks[krb + ds * 16];
        sc = __builtin_amdgcn_mfma_f32_32x32x16_bf16(ak, bq[ds], sc, 0, 0, 0);
      }
      // softmax (constant shift) + pack P^T groups: reg 4g+r -> key
      // (r&3)+8g+4hi; ua/ub[g] hold bf16(p) pairs
      int keyb = k0 + kt * 32 + 4 * hi - q + 2047;
      u32 ua[4], ub[4];
      for (int g = 0; g < 4; g++) {
        float p[4];
        for (int r = 0; r < 4; r++) {
          float v = sc[g * 4 + r];
          if (cflat) p[r] = __expf(v + cshift);
          else       p[r] = __expf(v + bias_s[tab_s[keyb + 8 * g + r]] - 40.f);
          l_run += p[r];
        }
        union { bf16x4 v4; u32 w[2]; } pk;
        pk.v4[0] = (bf16)p[0]; pk.v4[1] = (bf16)p[1];
        pk.v4[2] = (bf16)p[2]; pk.v4[3] = (bf16)p[3];
        ua[g] = pk.w[0]; ub[g] = pk.w[1];
      }
      // PV per 16-key chunk c: B-frag needs group G=2c+hi from BOTH lanes of
      // the (q, hi)<->(q, hi^1) pair -> exchange the partner-needed group.
      for (int c = 0; c < 2; c++) {
        u32 ka = hi ? ua[2 * c + 1] : ua[2 * c];
        u32 kb = hi ? ub[2 * c + 1] : ub[2 * c];
        u32 sa = hi ? ua[2 * c]     : ua[2 * c + 1];
        u32 sb = hi ? ub[2 * c]     : ub[2 * c + 1];
        u32 ra = (u32)__shfl_xor((int)sa, 32, 64);
        u32 rb = (u32)__shfl_xor((int)sb, 32, 64);
        union { u32 w[4]; bf16x8 v; } pf;
        pf.w[0] = hi ? ra : ka;   // j0-3 from hi_src=0 lane
        pf.w[1] = hi ? rb : kb;
        pf.w[2] = hi ? ka : ra;   // j4-7 from hi_src=1 lane
        pf.w[3] = hi ? kb : rb;
        for (int dt = 0; dt < 2; dt++) {
          bf16x8 av = *(const bf16x8*)&Vs[(dt * 32 + l31) * 136 + kt * 32 +
                                          c * 16 + hi * 8];
          ctx[dt] =
              __builtin_amdgcn_mfma_f32_32x32x16_bf16(av, pf.v, ctx[dt], 0, 0, 0);
        }
      }
    }
  }

  // lanes (q,0)/(q,1) hold disjoint key subsets: pair-sum l
  l_run += __shfl_xor(l_run, 32, 64);
  float rl = 1.f / l_run;
  // ctx^T C-layout: col=q=l31, row d = (r&3)+8g+4hi (+32dt)
  for (int dt = 0; dt < 2; dt++)
    for (int g = 0; g < 4; g++) {
      bf16x4 o;
      for (int r = 0; r < 4; r++) o[r] = (bf16)(ctx[dt][g * 4 + r] * rl);
      *(bf16x4*)&ctx_out[((size_t)(b * S + q)) * DM + h * HD + dt * 32 +
                         8 * g + 4 * hi] = o;
    }
}

// ---------------------------------------------------------------------------
extern "C" void kernel_launch(void* const* d_in, const int* in_sizes, int n_in,
                              void* d_out, int out_size, void* d_ws, size_t ws_size,
                              hipStream_t stream) {
  const float* x  = (const float*)d_in[0];
  const float* wq = (const float*)d_in[1];
  const float* wk = (const float*)d_in[2];
  const float* wv = (const float*)d_in[3];
  const float* wo = (const float*)d_in[4];
  const float* rb = (const float*)d_in[5];

  float* out = (float*)d_out;               // [2*2048, 2048] f32
  float* pb  = out + (size_t)2 * S * DM;    // [32, 2048, 2048] f32 — written LAST

  const size_t PROJ = (size_t)2 * S * DM;   // 8,388,608
  const size_t WSZ  = (size_t)DM * DM;      // 4,194,304
  bf16* arena = (bf16*)pb;                  // scratch aliased into pb region
  bf16* xb   = arena;
  bf16* wqb  = xb + PROJ;
  bf16* wkb  = wqb + WSZ;
  bf16* wvb  = wkb + WSZ;
  bf16* wob  = wvb + WSZ;
  bf16* qs   = wob + WSZ;
  bf16* ks   = qs + PROJ;
  bf16* vs   = ks + PROJ;                   // unused (V goes straight to vts)
  bf16* ctxs = vs + PROJ;
  bf16* vts  = ctxs + PROJ;                 // [B,H,64,S]
  int8_t* table = (int8_t*)d_ws;

  bucket_kernel<<<16, 256, 0, stream>>>(table);

  cast6<<<dim3((int)(WSZ / 4) / 256, 6), 256, 0, stream>>>(
      x, x + WSZ, wq, wk, wv, wo, arena);

  gemm_qkv<<<dim3(DM / 128, (2 * S) / 128, 3), 256, 0, stream>>>(
      xb, wqb, wkb, wvb, qs, vts);

  attn_kernel<<<dim3(S / 128, NH, 2), 256, 0, stream>>>(qs, ks, vts, rb, table,
                                                        ctxs);

  gemm_out<<<dim3(DM / 128, (2 * S) / 128), 256, 0, stream>>>(ctxs, wob, out);

  pb_kernel<<<dim3(S, NH), 256, 0, stream>>>(rb, table, pb);
}